// Round 11
// baseline (148.058 us; speedup 1.0000x reference)
//
#include <hip/hip_runtime.h>

// VQ-VAE quantize. Output BIT-EXACT vs numpy fp32 pipeline (proven R3-R10):
//   d_k = fl32( fl32(sumx + sume_k) - c_k ), c_k = sequential-k fp32 FMA of (2x).e,
//   idx = first-minimum argmin.
//
// R11: register-resident e-fragments. R8/R10 plateaued at ~83us because the
// per-chunk {vmcnt drain -> ds_write -> barrier -> ds_read+MFMA -> barrier}
// lockstep is the measured-~72%-overhead 2-phase schedule. Here: wave w holds
// its ENTIRE 128-k bf16 e-segment in 64 VGPRs (16 short8, loaded once from L2)
// + 4 x-strips; sweep A = 64 register-only MFMAs, no barriers/LDS in the loop.
// RMIN combined across waves once (k-ascending); sweep B recomputes s~ from the
// same registers (bit-identical) and appends candidates; bit-exact rescore.

#define N_ROWS   131072
#define NUM_EMB  1024
#define EMB_DIM  64
#define Q_ELEMS  8388608
#define THREADS  512
#define ROWS_PB  64           // block rows; each of 8 waves covers all 64 rows
#define KSEG     128          // k per wave
#define WCAP     1024

typedef short short8 __attribute__((ext_vector_type(8)));
typedef float f32x4  __attribute__((ext_vector_type(4)));

__device__ __forceinline__ unsigned short bf16_rne(float f) {
    unsigned u = __float_as_uint(f);
    u += 0x7fffu + ((u >> 16) & 1u);
    return (unsigned short)(u >> 16);
}

// monotone key for f32 (handles negatives): smaller float -> smaller key
__device__ __forceinline__ unsigned fkey(float d) {
    unsigned b = __float_as_uint(d);
    return b ^ (((unsigned)((int)b >> 31)) | 0x80000000u);
}

// numpy pairwise_sum (n=64) of fl32(a[i]*a[i]) — 8-accumulator order.
__device__ __forceinline__ float np_sq64(const float* a) {
    #pragma clang fp contract(off)
    float r0=a[0]*a[0],r1=a[1]*a[1],r2=a[2]*a[2],r3=a[3]*a[3];
    float r4=a[4]*a[4],r5=a[5]*a[5],r6=a[6]*a[6],r7=a[7]*a[7];
    #pragma unroll
    for (int i=8;i<64;i+=8){
        r0+=a[i+0]*a[i+0];r1+=a[i+1]*a[i+1];r2+=a[i+2]*a[i+2];r3+=a[i+3]*a[i+3];
        r4+=a[i+4]*a[i+4];r5+=a[i+5]*a[i+5];r6+=a[i+6]*a[i+6];r7+=a[i+7]*a[i+7];
    }
    return ((r0+r1)+(r2+r3))+((r4+r5)+(r6+r7));
}

// min over the 16 lanes of each DPP row (row_ror 1,2,4,8) — R7-R10-verified.
__device__ __forceinline__ float rotmin16(float v) {
    int x;
    x = __builtin_amdgcn_update_dpp(0, __float_as_int(v), 0x121, 0xf, 0xf, true);
    v = fminf(v, __int_as_float(x));
    x = __builtin_amdgcn_update_dpp(0, __float_as_int(v), 0x122, 0xf, 0xf, true);
    v = fminf(v, __int_as_float(x));
    x = __builtin_amdgcn_update_dpp(0, __float_as_int(v), 0x124, 0xf, 0xf, true);
    v = fminf(v, __int_as_float(x));
    x = __builtin_amdgcn_update_dpp(0, __float_as_int(v), 0x128, 0xf, 0xf, true);
    v = fminf(v, __int_as_float(x));
    return v;
}

// prep: sume (np order) + emb -> bf16, layout unit = chunk*1024 + gp*128 + krow
// (unit = 8 bf16 of dims gp*8..gp*8+7). Unchanged since R8 (verified).
__global__ __launch_bounds__(256) void vq_prep(const float* __restrict__ emb,
                                               float* __restrict__ sume,
                                               unsigned short* __restrict__ ehg) {
    int k = blockIdx.x * 256 + threadIdx.x;
    if (k < NUM_EMB) {
        sume[k] = np_sq64(emb + (k << 6));
        int c = k >> 7, krow = k & 127;
        #pragma unroll
        for (int gp = 0; gp < 8; ++gp) {
            short8 h;
            #pragma unroll
            for (int j = 0; j < 8; ++j)
                h[j] = (short)bf16_rne(emb[(k << 6) + gp*8 + j]);
            reinterpret_cast<short8*>(ehg)[c*1024 + gp*128 + krow] = h;
        }
    }
}

__global__ __launch_bounds__(THREADS, 2)
void vq_main(const float* __restrict__ x, const float* __restrict__ emb,
             const float* __restrict__ sume_g, const unsigned short* __restrict__ ehg,
             float* __restrict__ out_q, float* __restrict__ out_idx) {
    __shared__ float    LM[8][ROWS_PB];   // per-wave (k-seg) row minima
    __shared__ float    SA[ROWS_PB];
    __shared__ float    THR[ROWS_PB];
    __shared__ int      WL[WCAP];         // worklist (row<<10 | k)
    __shared__ float    WLD[WCAP];
    __shared__ unsigned DMIN[ROWS_PB];
    __shared__ unsigned KMIN[ROWS_PB];
    __shared__ int      SIDX[ROWS_PB];
    __shared__ unsigned WCNT;

    const int t   = threadIdx.x;
    const int w   = t >> 6;          // wave = k-segment 0..7 (k in [w*128, w*128+128))
    const int l   = t & 63;
    const int g   = l >> 4;          // K-dim quarter 0..3
    const int c16 = l & 15;
    const size_t blk_row0 = (size_t)blockIdx.x * ROWS_PB;

    // ---- e-fragments for this wave's whole k-segment: 16 short8 = 64 VGPR.
    // Same unit indexing as R10's LDS reads (chunk -> w, krow = lt*16+c16): verified.
    const short8* eg8 = reinterpret_cast<const short8*>(ehg);
    short8 eh[8][2];
    #pragma unroll
    for (int lt = 0; lt < 8; ++lt) {
        eh[lt][0] = eg8[w*1024 + (g    )*128 + lt*16 + c16];
        eh[lt][1] = eg8[w*1024 + (g + 4)*128 + lt*16 + c16];
    }
    // sume for this lane's k-column per tile (k = w*128 + lt*16 + c16).
    float smv[8];
    #pragma unroll
    for (int lt = 0; lt < 8; ++lt) smv[lt] = sume_g[w*KSEG + lt*16 + c16];

    if (t < ROWS_PB) { DMIN[t] = 0xFFFFFFFFu; KMIN[t] = 0xFFFFFFFFu; }
    if (t == 0) WCNT = 0u;

    // ---- x-fragments: 4 strips x 16 rows (A[m][kd], m = lane&15 = x-row;
    // kd = 8*(lane>>4)+j — R8/R10-verified). 2.0 folded. SA = sum|2x| per row.
    short8 ah[4][2];
    #pragma unroll
    for (int st = 0; st < 4; ++st) {
        const float* xp = x + (blk_row0 + (size_t)(st*16 + c16)) * EMB_DIM;
        const float4* xq = reinterpret_cast<const float4*>(xp);
        float sabs = 0.f;
        #pragma unroll
        for (int hf = 0; hf < 2; ++hf) {
            float4 u0 = xq[hf*8 + g*2 + 0];
            float4 u1 = xq[hf*8 + g*2 + 1];
            float vv[8] = {u0.x,u0.y,u0.z,u0.w,u1.x,u1.y,u1.z,u1.w};
            #pragma unroll
            for (int j = 0; j < 8; ++j) {
                float v = 2.0f * vv[j];
                sabs += fabsf(v);
                ah[st][hf][j] = (short)bf16_rne(v);
            }
        }
        sabs += __shfl_xor(sabs, 16);
        sabs += __shfl_xor(sabs, 32);
        if (w == 0 && g == 0) SA[st*16 + c16] = sabs;
    }

    // ---- sweep A: 64 register-only MFMAs; running min per (strip, reg).
    float stash[4][4];
    #pragma unroll
    for (int st = 0; st < 4; ++st)
        #pragma unroll
        for (int r = 0; r < 4; ++r) stash[st][r] = 3.4e38f;

    #pragma unroll
    for (int lt = 0; lt < 8; ++lt) {
        #pragma unroll
        for (int st = 0; st < 4; ++st) {
            f32x4 a = {0.f,0.f,0.f,0.f};
            a = __builtin_amdgcn_mfma_f32_16x16x32_bf16(ah[st][0], eh[lt][0], a, 0,0,0);
            a = __builtin_amdgcn_mfma_f32_16x16x32_bf16(ah[st][1], eh[lt][1], a, 0,0,0);
            #pragma unroll
            for (int r = 0; r < 4; ++r)
                stash[st][r] = fminf(stash[st][r], smv[lt] - a[r]);
        }
    }

    // D-row = st*16 + 4*g + r, D-col = c16 = k (verified); min over cols via DPP.
    #pragma unroll
    for (int st = 0; st < 4; ++st) {
        #pragma unroll
        for (int r = 0; r < 4; ++r) {
            float v = rotmin16(stash[st][r]);
            if (c16 == 0) LM[w][st*16 + 4*g + r] = v;
        }
    }
    __syncthreads();
    if (t < ROWS_PB) {
        float bm = LM[0][t];
        #pragma unroll
        for (int w2 = 1; w2 < 8; ++w2) bm = fminf(bm, LM[w2][t]);
        // W = SA*2^-16 (two-sided bf16 product err, conservative) + grid/acc slack
        THR[t] = bm + (SA[t] * 1.6e-5f + 4.0e-5f);
    }
    __syncthreads();

    float thrv[4][4], thrmax[4];
    #pragma unroll
    for (int st = 0; st < 4; ++st) {
        #pragma unroll
        for (int r = 0; r < 4; ++r) thrv[st][r] = THR[st*16 + 4*g + r];
        thrmax[st] = fmaxf(fmaxf(thrv[st][0], thrv[st][1]),
                           fmaxf(thrv[st][2], thrv[st][3]));
    }

    // ---- sweep B: recompute s~ from the SAME registers (bit-identical);
    // append candidates. Strip-level min4 pre-test keeps branches off hot path.
    #pragma unroll
    for (int lt = 0; lt < 8; ++lt) {
        const int kk = w*KSEG + lt*16 + c16;     // this lane's k-column
        #pragma unroll
        for (int st = 0; st < 4; ++st) {
            f32x4 a = {0.f,0.f,0.f,0.f};
            a = __builtin_amdgcn_mfma_f32_16x16x32_bf16(ah[st][0], eh[lt][0], a, 0,0,0);
            a = __builtin_amdgcn_mfma_f32_16x16x32_bf16(ah[st][1], eh[lt][1], a, 0,0,0);
            float s0 = smv[lt] - a[0], s1 = smv[lt] - a[1];
            float s2 = smv[lt] - a[2], s3 = smv[lt] - a[3];
            float m4 = fminf(fminf(s0, s1), fminf(s2, s3));
            if (m4 < thrmax[st]) {
                if (s0 < thrv[st][0]) { unsigned q = atomicAdd(&WCNT,1u); if (q<WCAP) WL[q] = ((st*16+4*g+0)<<10)|kk; }
                if (s1 < thrv[st][1]) { unsigned q = atomicAdd(&WCNT,1u); if (q<WCAP) WL[q] = ((st*16+4*g+1)<<10)|kk; }
                if (s2 < thrv[st][2]) { unsigned q = atomicAdd(&WCNT,1u); if (q<WCAP) WL[q] = ((st*16+4*g+2)<<10)|kk; }
                if (s3 < thrv[st][3]) { unsigned q = atomicAdd(&WCNT,1u); if (q<WCAP) WL[q] = ((st*16+4*g+3)<<10)|kk; }
            }
        }
    }
    __syncthreads();

    const unsigned wc = WCNT;                  // uniform (post-barrier)

    if (wc <= WCAP) {
        // lane-parallel BIT-EXACT rescore (~1.5 pairs/row -> ~90/block).
        for (unsigned q = t; q < wc; q += THREADS) {
            int pr = WL[q]; int row = pr >> 10; int kk = pr & 1023;
            const float* xr = x + (blk_row0 + (size_t)row) * EMB_DIM;
            const float* er = emb + (kk << 6);
            float sumx = np_sq64(xr);
            float cc = 0.f;
            #pragma unroll 8
            for (int i = 0; i < EMB_DIM; ++i)
                cc = fmaf(2.0f * xr[i], er[i], cc);   // sgemm sequential-k order
            float d;
            {
                #pragma clang fp contract(off)
                d = (sumx + sume_g[kk]) - cc;         // fl32 grid @ ~64
            }
            WLD[q] = d;
            atomicMin(&DMIN[row], fkey(d));
        }
        __syncthreads();
        for (unsigned q = t; q < wc; q += THREADS) {
            int pr = WL[q]; int row = pr >> 10; int kk = pr & 1023;
            if (fkey(WLD[q]) == DMIN[row])
                atomicMin(&KMIN[row], (unsigned)kk);  // ties -> smallest k = first-min
        }
        __syncthreads();
        if (t < ROWS_PB) {
            int bk = (int)KMIN[t];
            SIDX[t] = bk;
            out_idx[blk_row0 + t] = (float)bk;
        }
    } else {
        // cold exact fallback (worklist overflow; never on sane data).
        if (t < ROWS_PB) {
            const float* xr = x + (blk_row0 + (size_t)t) * EMB_DIM;
            float sumx = np_sq64(xr);
            volatile const float* xv = xr;
            float bm = 3.4e38f; int bb = 0;
            for (int kk = 0; kk < NUM_EMB; ++kk) {
                const float* er = emb + (kk << 6);
                float cc = 0.f;
                for (int i = 0; i < EMB_DIM; ++i)
                    cc = fmaf(2.0f * xv[i], er[i], cc);
                {
                    #pragma clang fp contract(off)
                    float d = (sumx + sume_g[kk]) - cc;
                    if (d < bm) { bm = d; bb = kk; }
                }
            }
            SIDX[t] = bb;
            out_idx[blk_row0 + t] = (float)bb;
        }
    }
    __syncthreads();

    // ---- coalesced gather: quantized[row] = emb[idx[row]]
    const float4* emb4 = reinterpret_cast<const float4*>(emb);
    float4* q4 = reinterpret_cast<float4*>(out_q + blk_row0 * EMB_DIM);
    #pragma unroll
    for (int i = 0; i < 2; ++i) {
        int e4 = t + i * THREADS;     // 1024 float4 per block
        int rr = e4 >> 4, cc2 = e4 & 15;
        q4[e4] = emb4[SIDX[rr]*16 + cc2];
    }
}

extern "C" void kernel_launch(void* const* d_in, const int* in_sizes, int n_in,
                              void* d_out, int out_size, void* d_ws, size_t ws_size,
                              hipStream_t stream) {
    const float* x   = (const float*)d_in[0];
    const float* emb = (const float*)d_in[1];
    float* out_q   = (float*)d_out;
    float* out_idx = out_q + Q_ELEMS;
    float*          sume = (float*)d_ws;                          // 4 KB
    unsigned short* ehg  = (unsigned short*)((char*)d_ws + 4096); // 128 KB bf16 emb

    vq_prep<<<dim3(NUM_EMB / 256), dim3(256), 0, stream>>>(emb, sume, ehg);
    vq_main<<<dim3(N_ROWS / ROWS_PB), dim3(THREADS), 0, stream>>>(x, emb, sume, ehg,
                                                                  out_q, out_idx);
}

// Round 12
// 101.930 us; speedup vs baseline: 1.4526x; 1.4526x over previous
//
#include <hip/hip_runtime.h>

// VQ-VAE quantize. Output BIT-EXACT vs numpy fp32 pipeline (proven R3-R11):
//   d_k = fl32( fl32(sumx + sume_k) - c_k ), c_k = sequential-k fp32 FMA of (2x).e,
//   idx = first-minimum argmin.
//
// R12: whole bf16 codebook resident in LDS (128 KB of the 160 KB/CU), staged
// ONCE per block. 256 blocks x 512 rows (8 waves x 64 rows, each wave covers
// ALL 1024 k for its own rows -> no cross-wave combine). Sweep A = 64 iters of
// {2 ds_read_b128 + 8 reg-only MFMA + fmin} with ZERO barriers (R10's 2-phase
// stage/barrier lockstep was the ~72%-overhead wall; R11's global-resident regs
// traded it for occupancy+L2-refetch walls). Sweep B recomputes s~ bit-identically
// from the same LDS and appends candidates < RMIN+W; lane-parallel exact rescore.

#define N_ROWS   131072
#define NUM_EMB  1024
#define EMB_DIM  64
#define Q_ELEMS  8388608
#define THREADS  512
#define ROWS_PB  512          // 8 waves x 64 rows
#define WCAP     3072

typedef short short8 __attribute__((ext_vector_type(8)));
typedef float f32x4  __attribute__((ext_vector_type(4)));

__device__ __forceinline__ unsigned short bf16_rne(float f) {
    unsigned u = __float_as_uint(f);
    u += 0x7fffu + ((u >> 16) & 1u);
    return (unsigned short)(u >> 16);
}

// monotone key for f32 (handles negatives): smaller float -> smaller key
__device__ __forceinline__ unsigned fkey(float d) {
    unsigned b = __float_as_uint(d);
    return b ^ (((unsigned)((int)b >> 31)) | 0x80000000u);
}

// numpy pairwise_sum (n=64) of fl32(a[i]*a[i]) — 8-accumulator order.
__device__ __forceinline__ float np_sq64(const float* a) {
    #pragma clang fp contract(off)
    float r0=a[0]*a[0],r1=a[1]*a[1],r2=a[2]*a[2],r3=a[3]*a[3];
    float r4=a[4]*a[4],r5=a[5]*a[5],r6=a[6]*a[6],r7=a[7]*a[7];
    #pragma unroll
    for (int i=8;i<64;i+=8){
        r0+=a[i+0]*a[i+0];r1+=a[i+1]*a[i+1];r2+=a[i+2]*a[i+2];r3+=a[i+3]*a[i+3];
        r4+=a[i+4]*a[i+4];r5+=a[i+5]*a[i+5];r6+=a[i+6]*a[i+6];r7+=a[i+7]*a[i+7];
    }
    return ((r0+r1)+(r2+r3))+((r4+r5)+(r6+r7));
}

// min over the 16 lanes of each DPP row (row_ror 1,2,4,8) — R7-R11-verified.
__device__ __forceinline__ float rotmin16(float v) {
    int x;
    x = __builtin_amdgcn_update_dpp(0, __float_as_int(v), 0x121, 0xf, 0xf, true);
    v = fminf(v, __int_as_float(x));
    x = __builtin_amdgcn_update_dpp(0, __float_as_int(v), 0x122, 0xf, 0xf, true);
    v = fminf(v, __int_as_float(x));
    x = __builtin_amdgcn_update_dpp(0, __float_as_int(v), 0x124, 0xf, 0xf, true);
    v = fminf(v, __int_as_float(x));
    x = __builtin_amdgcn_update_dpp(0, __float_as_int(v), 0x128, 0xf, 0xf, true);
    v = fminf(v, __int_as_float(x));
    return v;
}

// prep: sume (np order) + emb -> bf16, layout unit = chunk*1024 + gp*128 + krow
// (unit = 8 bf16 of dims gp*8..gp*8+7), chunk = k>>7, krow = k&127. Verified R8+.
__global__ __launch_bounds__(256) void vq_prep(const float* __restrict__ emb,
                                               float* __restrict__ sume,
                                               unsigned short* __restrict__ ehg) {
    int k = blockIdx.x * 256 + threadIdx.x;
    if (k < NUM_EMB) {
        sume[k] = np_sq64(emb + (k << 6));
        int c = k >> 7, krow = k & 127;
        #pragma unroll
        for (int gp = 0; gp < 8; ++gp) {
            short8 h;
            #pragma unroll
            for (int j = 0; j < 8; ++j)
                h[j] = (short)bf16_rne(emb[(k << 6) + gp*8 + j]);
            reinterpret_cast<short8*>(ehg)[c*1024 + gp*128 + krow] = h;
        }
    }
}

__global__ __launch_bounds__(THREADS, 2)
void vq_main(const float* __restrict__ x, const float* __restrict__ emb,
             const float* __restrict__ sume_g, const unsigned short* __restrict__ ehg,
             float* __restrict__ out_q, float* __restrict__ out_idx) {
    __shared__ int4     EH4[8192];        // 128 KB: ENTIRE bf16 codebook
    __shared__ float    SUME[NUM_EMB];    // 4 KB
    __shared__ float    RMIN[ROWS_PB];    // 2 KB (becomes THR in place)
    __shared__ float    SA[ROWS_PB];      // 2 KB
    __shared__ int      WL[WCAP];         // 12 KB worklist (row<<10 | k)
    __shared__ unsigned DMIN[ROWS_PB];    // 2 KB
    __shared__ unsigned KMIN[ROWS_PB];    // 2 KB
    __shared__ int      SIDX[ROWS_PB];    // 2 KB
    __shared__ unsigned WCNT;

    const int t   = threadIdx.x;
    const int w   = t >> 6;          // wave 0..7: owns rows w*64..w*64+63
    const int l   = t & 63;
    const int g   = l >> 4;          // K-dim quarter 0..3
    const int c16 = l & 15;
    const size_t blk_row0 = (size_t)blockIdx.x * ROWS_PB;

    // ---- stage whole codebook + sume ONCE (L2-resident source; 256 B/thread).
    const int4* eg4 = reinterpret_cast<const int4*>(ehg);
    #pragma unroll
    for (int i = 0; i < 16; ++i) EH4[t + i*THREADS] = eg4[t + i*THREADS];
    SUME[t]           = sume_g[t];
    SUME[t + THREADS] = sume_g[t + THREADS];
    DMIN[t] = 0xFFFFFFFFu; KMIN[t] = 0xFFFFFFFFu;
    if (t == 0) WCNT = 0u;

    // ---- x-fragments: 4 strips x 16 rows (A[m][kd], m = lane&15 = x-row;
    // kd = 8*(lane>>4)+j — R8-R11-verified). 2.0 folded. SA = sum|2x| per row.
    short8 ah[4][2];
    #pragma unroll
    for (int st = 0; st < 4; ++st) {
        const float* xp = x + (blk_row0 + (size_t)(w*64 + st*16 + c16)) * EMB_DIM;
        float sabs = 0.f;
        #pragma unroll
        for (int hf = 0; hf < 2; ++hf) {
            #pragma unroll
            for (int j = 0; j < 8; ++j) {
                float v = 2.0f * xp[hf*32 + g*8 + j];
                sabs += fabsf(v);
                ah[st][hf][j] = (short)bf16_rne(v);
            }
        }
        sabs += __shfl_xor(sabs, 16);
        sabs += __shfl_xor(sabs, 32);
        if (g == 0) SA[w*64 + st*16 + c16] = sabs;
    }
    __syncthreads();    // EH/SUME/SA ready

    // ---- sweep A: 64 k-tiles x 4 strips, reg-only MFMA, NO barriers.
    float stash[4][4];
    #pragma unroll
    for (int st = 0; st < 4; ++st)
        #pragma unroll
        for (int r = 0; r < 4; ++r) stash[st][r] = 3.4e38f;

    const short8* EHs = reinterpret_cast<const short8*>(EH4);
    #pragma unroll 4
    for (int lt = 0; lt < 64; ++lt) {
        const int ub = (lt >> 3)*1024 + (lt & 7)*16 + c16;   // chunk/krow decode
        short8 bh0 = EHs[ub + (g    )*128];
        short8 bh1 = EHs[ub + (g + 4)*128];
        float scol = SUME[lt*16 + c16];
        #pragma unroll
        for (int st = 0; st < 4; ++st) {
            f32x4 a = {0.f,0.f,0.f,0.f};
            a = __builtin_amdgcn_mfma_f32_16x16x32_bf16(ah[st][0], bh0, a, 0,0,0);
            a = __builtin_amdgcn_mfma_f32_16x16x32_bf16(ah[st][1], bh1, a, 0,0,0);
            #pragma unroll
            for (int r = 0; r < 4; ++r)
                stash[st][r] = fminf(stash[st][r], scol - a[r]);
        }
    }

    // D-row = st*16 + 4*g + r, D-col = c16 = k (verified); min over cols via DPP.
    #pragma unroll
    for (int st = 0; st < 4; ++st) {
        #pragma unroll
        for (int r = 0; r < 4; ++r) {
            float v = rotmin16(stash[st][r]);
            if (c16 == 0) RMIN[w*64 + st*16 + 4*g + r] = v;
        }
    }
    __syncthreads();
    // THR in place: W = SA*2^-16 (two-sided bf16 product err, conservative) + slack
    RMIN[t] = RMIN[t] + (SA[t] * 1.6e-5f + 4.0e-5f);
    __syncthreads();

    float thrv[4][4], thrmax[4];
    #pragma unroll
    for (int st = 0; st < 4; ++st) {
        #pragma unroll
        for (int r = 0; r < 4; ++r) thrv[st][r] = RMIN[w*64 + st*16 + 4*g + r];
        thrmax[st] = fmaxf(fmaxf(thrv[st][0], thrv[st][1]),
                           fmaxf(thrv[st][2], thrv[st][3]));
    }

    // ---- sweep B: recompute s~ (bit-identical: same instrs, same inputs);
    // append candidates. Strip-level min4 pre-test keeps branches off hot path.
    #pragma unroll 2
    for (int lt = 0; lt < 64; ++lt) {
        const int ub = (lt >> 3)*1024 + (lt & 7)*16 + c16;
        short8 bh0 = EHs[ub + (g    )*128];
        short8 bh1 = EHs[ub + (g + 4)*128];
        float scol = SUME[lt*16 + c16];
        const int kk = lt*16 + c16;              // this lane's k-column
        #pragma unroll
        for (int st = 0; st < 4; ++st) {
            f32x4 a = {0.f,0.f,0.f,0.f};
            a = __builtin_amdgcn_mfma_f32_16x16x32_bf16(ah[st][0], bh0, a, 0,0,0);
            a = __builtin_amdgcn_mfma_f32_16x16x32_bf16(ah[st][1], bh1, a, 0,0,0);
            float s0 = scol - a[0], s1 = scol - a[1];
            float s2 = scol - a[2], s3 = scol - a[3];
            float m4 = fminf(fminf(s0, s1), fminf(s2, s3));
            if (m4 < thrmax[st]) {
                const int rb = (w*64 + st*16 + 4*g) << 10;
                if (s0 < thrv[st][0]) { unsigned q = atomicAdd(&WCNT,1u); if (q<WCAP) WL[q] = rb + (0<<10) + kk; }
                if (s1 < thrv[st][1]) { unsigned q = atomicAdd(&WCNT,1u); if (q<WCAP) WL[q] = rb + (1<<10) + kk; }
                if (s2 < thrv[st][2]) { unsigned q = atomicAdd(&WCNT,1u); if (q<WCAP) WL[q] = rb + (2<<10) + kk; }
                if (s3 < thrv[st][3]) { unsigned q = atomicAdd(&WCNT,1u); if (q<WCAP) WL[q] = rb + (3<<10) + kk; }
            }
        }
    }
    __syncthreads();

    const unsigned wc = WCNT;                      // uniform (post-barrier)
    float* WLD = reinterpret_cast<float*>(EH4);    // EH dead: alias rescore scratch

    if (wc <= WCAP) {
        // lane-parallel BIT-EXACT rescore (~2.4 pairs/row -> ~2.4/thread).
        for (unsigned q = t; q < wc; q += THREADS) {
            int pr = WL[q]; int row = pr >> 10; int kk = pr & 1023;
            const float* xr = x + (blk_row0 + (size_t)row) * EMB_DIM;
            const float* er = emb + (kk << 6);
            float sumx = np_sq64(xr);
            float cc = 0.f;
            #pragma unroll 8
            for (int i = 0; i < EMB_DIM; ++i)
                cc = fmaf(2.0f * xr[i], er[i], cc);   // sgemm sequential-k order
            float d;
            {
                #pragma clang fp contract(off)
                d = (sumx + SUME[kk]) - cc;           // fl32 grid @ ~64
            }
            WLD[q] = d;
            atomicMin(&DMIN[row], fkey(d));
        }
        __syncthreads();
        for (unsigned q = t; q < wc; q += THREADS) {
            int pr = WL[q]; int row = pr >> 10; int kk = pr & 1023;
            if (fkey(WLD[q]) == DMIN[row])
                atomicMin(&KMIN[row], (unsigned)kk);  // ties -> smallest k = first-min
        }
        __syncthreads();
        int bk = (int)KMIN[t];
        SIDX[t] = bk;
        out_idx[blk_row0 + t] = (float)bk;
    } else {
        // cold exact fallback (worklist overflow; never on sane data).
        const float* xr = x + (blk_row0 + (size_t)t) * EMB_DIM;
        float sumx = np_sq64(xr);
        volatile const float* xv = xr;
        float bm = 3.4e38f; int bb = 0;
        for (int kk = 0; kk < NUM_EMB; ++kk) {
            const float* er = emb + (kk << 6);
            float cc = 0.f;
            for (int i = 0; i < EMB_DIM; ++i)
                cc = fmaf(2.0f * xv[i], er[i], cc);
            {
                #pragma clang fp contract(off)
                float d = (sumx + SUME[kk]) - cc;
                if (d < bm) { bm = d; bb = kk; }
            }
        }
        SIDX[t] = bb;
        out_idx[blk_row0 + t] = (float)bb;
    }
    __syncthreads();

    // ---- coalesced gather: quantized[row] = emb[idx[row]]
    const float4* emb4 = reinterpret_cast<const float4*>(emb);
    float4* q4 = reinterpret_cast<float4*>(out_q + blk_row0 * EMB_DIM);
    #pragma unroll
    for (int i = 0; i < 16; ++i) {
        int e4 = t + i * THREADS;     // 8192 float4 per block
        int rr = e4 >> 4, cc2 = e4 & 15;
        q4[e4] = emb4[SIDX[rr]*16 + cc2];
    }
}

extern "C" void kernel_launch(void* const* d_in, const int* in_sizes, int n_in,
                              void* d_out, int out_size, void* d_ws, size_t ws_size,
                              hipStream_t stream) {
    const float* x   = (const float*)d_in[0];
    const float* emb = (const float*)d_in[1];
    float* out_q   = (float*)d_out;
    float* out_idx = out_q + Q_ELEMS;
    float*          sume = (float*)d_ws;                          // 4 KB
    unsigned short* ehg  = (unsigned short*)((char*)d_ws + 4096); // 128 KB bf16 emb

    vq_prep<<<dim3(NUM_EMB / 256), dim3(256), 0, stream>>>(emb, sume, ehg);
    vq_main<<<dim3(N_ROWS / ROWS_PB), dim3(THREADS), 0, stream>>>(x, emb, sume, ehg,
                                                                  out_q, out_idx);
}

// Round 13
// 86.345 us; speedup vs baseline: 1.7147x; 1.1805x over previous
//
#include <hip/hip_runtime.h>

// VQ-VAE quantize. Output BIT-EXACT vs numpy fp32 pipeline (proven R3-R12):
//   d_k = fl32( fl32(sumx + sume_k) - c_k ), c_k = sequential-k fp32 FMA of (2x).e,
//   idx = first-minimum argmin.
//
// R13 = R12 (whole 128KB bf16 codebook in LDS, barrier-free MFMA sweep) but with
// 16 waves/block (1024 thr) = 4 waves/SIMD, partitioned 8 row-groups x 2 k-halves.
// R10 (TLP+barriers)=83us, R12 (no barriers, 2 waves/SIMD)=102us -> this round
// combines no-barrier sweep WITH 4 waves/SIMD. Same per-CU ds traffic as R12.
// Two k-half partial minima combined once in LDS (outside the sweep).

#define N_ROWS   131072
#define NUM_EMB  1024
#define EMB_DIM  64
#define Q_ELEMS  8388608
#define THREADS  1024
#define ROWS_PB  512          // 8 row-groups x 64 rows; 2 k-halves
#define WCAP     3072

typedef short short8 __attribute__((ext_vector_type(8)));
typedef float f32x4  __attribute__((ext_vector_type(4)));

__device__ __forceinline__ unsigned short bf16_rne(float f) {
    unsigned u = __float_as_uint(f);
    u += 0x7fffu + ((u >> 16) & 1u);
    return (unsigned short)(u >> 16);
}

// monotone key for f32 (handles negatives): smaller float -> smaller key
__device__ __forceinline__ unsigned fkey(float d) {
    unsigned b = __float_as_uint(d);
    return b ^ (((unsigned)((int)b >> 31)) | 0x80000000u);
}

// numpy pairwise_sum (n=64) of fl32(a[i]*a[i]) — 8-accumulator order.
__device__ __forceinline__ float np_sq64(const float* a) {
    #pragma clang fp contract(off)
    float r0=a[0]*a[0],r1=a[1]*a[1],r2=a[2]*a[2],r3=a[3]*a[3];
    float r4=a[4]*a[4],r5=a[5]*a[5],r6=a[6]*a[6],r7=a[7]*a[7];
    #pragma unroll
    for (int i=8;i<64;i+=8){
        r0+=a[i+0]*a[i+0];r1+=a[i+1]*a[i+1];r2+=a[i+2]*a[i+2];r3+=a[i+3]*a[i+3];
        r4+=a[i+4]*a[i+4];r5+=a[i+5]*a[i+5];r6+=a[i+6]*a[i+6];r7+=a[i+7]*a[i+7];
    }
    return ((r0+r1)+(r2+r3))+((r4+r5)+(r6+r7));
}

// min over the 16 lanes of each DPP row (row_ror 1,2,4,8) — R7-R12-verified.
__device__ __forceinline__ float rotmin16(float v) {
    int x;
    x = __builtin_amdgcn_update_dpp(0, __float_as_int(v), 0x121, 0xf, 0xf, true);
    v = fminf(v, __int_as_float(x));
    x = __builtin_amdgcn_update_dpp(0, __float_as_int(v), 0x122, 0xf, 0xf, true);
    v = fminf(v, __int_as_float(x));
    x = __builtin_amdgcn_update_dpp(0, __float_as_int(v), 0x124, 0xf, 0xf, true);
    v = fminf(v, __int_as_float(x));
    x = __builtin_amdgcn_update_dpp(0, __float_as_int(v), 0x128, 0xf, 0xf, true);
    v = fminf(v, __int_as_float(x));
    return v;
}

// prep: sume (np order) + emb -> bf16, layout unit = chunk*1024 + gp*128 + krow
// (unit = 8 bf16 of dims gp*8..gp*8+7), chunk = k>>7, krow = k&127. Verified R8+.
__global__ __launch_bounds__(256) void vq_prep(const float* __restrict__ emb,
                                               float* __restrict__ sume,
                                               unsigned short* __restrict__ ehg) {
    int k = blockIdx.x * 256 + threadIdx.x;
    if (k < NUM_EMB) {
        sume[k] = np_sq64(emb + (k << 6));
        int c = k >> 7, krow = k & 127;
        #pragma unroll
        for (int gp = 0; gp < 8; ++gp) {
            short8 h;
            #pragma unroll
            for (int j = 0; j < 8; ++j)
                h[j] = (short)bf16_rne(emb[(k << 6) + gp*8 + j]);
            reinterpret_cast<short8*>(ehg)[c*1024 + gp*128 + krow] = h;
        }
    }
}

__global__ __launch_bounds__(THREADS)
void vq_main(const float* __restrict__ x, const float* __restrict__ emb,
             const float* __restrict__ sume_g, const unsigned short* __restrict__ ehg,
             float* __restrict__ out_q, float* __restrict__ out_idx) {
    __shared__ int4     EH4[8192];        // 128 KB: ENTIRE bf16 codebook
    __shared__ float    SUME[NUM_EMB];    // 4 KB
    __shared__ float    LM[2][ROWS_PB];   // 4 KB per-k-half row minima
    __shared__ float    THR[ROWS_PB];     // 2 KB
    __shared__ float    SA[ROWS_PB];      // 2 KB
    __shared__ int      WL[WCAP];         // 12 KB worklist (row<<10 | k)
    __shared__ unsigned DMIN[ROWS_PB];    // 2 KB
    __shared__ unsigned KMIN[ROWS_PB];    // 2 KB
    __shared__ int      SIDX[ROWS_PB];    // 2 KB
    __shared__ unsigned WCNT;

    const int t    = threadIdx.x;
    const int w    = t >> 6;         // wave 0..15
    const int w8   = w & 7;          // row-group: rows w8*64 .. w8*64+63
    const int half = w >> 3;         // k-half: k in [half*512, half*512+512)
    const int l    = t & 63;
    const int g    = l >> 4;         // K-dim quarter 0..3
    const int c16  = l & 15;
    const size_t blk_row0 = (size_t)blockIdx.x * ROWS_PB;

    // ---- stage whole codebook + sume ONCE (L2-resident source).
    const int4* eg4 = reinterpret_cast<const int4*>(ehg);
    #pragma unroll
    for (int i = 0; i < 8; ++i) EH4[t + i*THREADS] = eg4[t + i*THREADS];
    SUME[t] = sume_g[t];
    if (t < ROWS_PB) { DMIN[t] = 0xFFFFFFFFu; KMIN[t] = 0xFFFFFFFFu; }
    if (t == 0) WCNT = 0u;

    // ---- x-fragments: 4 strips x 16 rows (A[m][kd], m = lane&15 = x-row;
    // kd = 8*(lane>>4)+j — R8-R12-verified). float4 loads (R11-verified indexing).
    // 2.0 folded. SA = sum|2x| per row (written by half 0 only).
    short8 ah[4][2];
    #pragma unroll
    for (int st = 0; st < 4; ++st) {
        const float4* xq = reinterpret_cast<const float4*>(
            x + (blk_row0 + (size_t)(w8*64 + st*16 + c16)) * EMB_DIM);
        float sabs = 0.f;
        #pragma unroll
        for (int hf = 0; hf < 2; ++hf) {
            float4 u0 = xq[hf*8 + g*2 + 0];
            float4 u1 = xq[hf*8 + g*2 + 1];
            float vv[8] = {u0.x,u0.y,u0.z,u0.w,u1.x,u1.y,u1.z,u1.w};
            #pragma unroll
            for (int j = 0; j < 8; ++j) {
                float v = 2.0f * vv[j];
                sabs += fabsf(v);
                ah[st][hf][j] = (short)bf16_rne(v);
            }
        }
        sabs += __shfl_xor(sabs, 16);
        sabs += __shfl_xor(sabs, 32);
        if (g == 0 && half == 0) SA[w8*64 + st*16 + c16] = sabs;
    }
    __syncthreads();    // EH/SUME/SA ready

    // ---- sweep A: 32 k-tiles x 4 strips, reg-only MFMA, NO barriers.
    float stash[4][4];
    #pragma unroll
    for (int st = 0; st < 4; ++st)
        #pragma unroll
        for (int r = 0; r < 4; ++r) stash[st][r] = 3.4e38f;

    const short8* EHs = reinterpret_cast<const short8*>(EH4);
    #pragma unroll 4
    for (int lt = 0; lt < 32; ++lt) {
        const int ltg = half*32 + lt;
        const int ub  = (ltg >> 3)*1024 + (ltg & 7)*16 + c16;   // chunk/krow decode
        short8 bh0 = EHs[ub + (g    )*128];
        short8 bh1 = EHs[ub + (g + 4)*128];
        float scol = SUME[ltg*16 + c16];
        #pragma unroll
        for (int st = 0; st < 4; ++st) {
            f32x4 a = {0.f,0.f,0.f,0.f};
            a = __builtin_amdgcn_mfma_f32_16x16x32_bf16(ah[st][0], bh0, a, 0,0,0);
            a = __builtin_amdgcn_mfma_f32_16x16x32_bf16(ah[st][1], bh1, a, 0,0,0);
            #pragma unroll
            for (int r = 0; r < 4; ++r)
                stash[st][r] = fminf(stash[st][r], scol - a[r]);
        }
    }

    // D-row = st*16 + 4*g + r, D-col = c16 = k (verified); min over cols via DPP.
    #pragma unroll
    for (int st = 0; st < 4; ++st) {
        #pragma unroll
        for (int r = 0; r < 4; ++r) {
            float v = rotmin16(stash[st][r]);
            if (c16 == 0) LM[half][w8*64 + st*16 + 4*g + r] = v;
        }
    }
    __syncthreads();
    if (t < ROWS_PB) {
        float bm = fminf(LM[0][t], LM[1][t]);
        // W = SA*2^-16 (two-sided bf16 product err, conservative) + grid/acc slack
        THR[t] = bm + (SA[t] * 1.6e-5f + 4.0e-5f);
    }
    __syncthreads();

    float thrv[4][4], thrmax[4];
    #pragma unroll
    for (int st = 0; st < 4; ++st) {
        #pragma unroll
        for (int r = 0; r < 4; ++r) thrv[st][r] = THR[w8*64 + st*16 + 4*g + r];
        thrmax[st] = fmaxf(fmaxf(thrv[st][0], thrv[st][1]),
                           fmaxf(thrv[st][2], thrv[st][3]));
    }

    // ---- sweep B: recompute s~ (bit-identical: same instrs, same inputs);
    // append candidates. Strip-level min4 pre-test keeps branches off hot path.
    #pragma unroll 2
    for (int lt = 0; lt < 32; ++lt) {
        const int ltg = half*32 + lt;
        const int ub  = (ltg >> 3)*1024 + (ltg & 7)*16 + c16;
        short8 bh0 = EHs[ub + (g    )*128];
        short8 bh1 = EHs[ub + (g + 4)*128];
        float scol = SUME[ltg*16 + c16];
        const int kk = ltg*16 + c16;             // this lane's k-column
        #pragma unroll
        for (int st = 0; st < 4; ++st) {
            f32x4 a = {0.f,0.f,0.f,0.f};
            a = __builtin_amdgcn_mfma_f32_16x16x32_bf16(ah[st][0], bh0, a, 0,0,0);
            a = __builtin_amdgcn_mfma_f32_16x16x32_bf16(ah[st][1], bh1, a, 0,0,0);
            float s0 = scol - a[0], s1 = scol - a[1];
            float s2 = scol - a[2], s3 = scol - a[3];
            float m4 = fminf(fminf(s0, s1), fminf(s2, s3));
            if (m4 < thrmax[st]) {
                const int rb = (w8*64 + st*16 + 4*g) << 10;
                if (s0 < thrv[st][0]) { unsigned q = atomicAdd(&WCNT,1u); if (q<WCAP) WL[q] = rb + (0<<10) + kk; }
                if (s1 < thrv[st][1]) { unsigned q = atomicAdd(&WCNT,1u); if (q<WCAP) WL[q] = rb + (1<<10) + kk; }
                if (s2 < thrv[st][2]) { unsigned q = atomicAdd(&WCNT,1u); if (q<WCAP) WL[q] = rb + (2<<10) + kk; }
                if (s3 < thrv[st][3]) { unsigned q = atomicAdd(&WCNT,1u); if (q<WCAP) WL[q] = rb + (3<<10) + kk; }
            }
        }
    }
    __syncthreads();

    const unsigned wc = WCNT;                      // uniform (post-barrier)
    float* WLD = reinterpret_cast<float*>(EH4);    // EH dead: alias rescore scratch

    if (wc <= WCAP) {
        // lane-parallel BIT-EXACT rescore (~2.4 pairs/row -> ~1.2/thread).
        for (unsigned q = t; q < wc; q += THREADS) {
            int pr = WL[q]; int row = pr >> 10; int kk = pr & 1023;
            const float* xr = x + (blk_row0 + (size_t)row) * EMB_DIM;
            const float* er = emb + (kk << 6);
            float sumx = np_sq64(xr);
            float cc = 0.f;
            #pragma unroll 8
            for (int i = 0; i < EMB_DIM; ++i)
                cc = fmaf(2.0f * xr[i], er[i], cc);   // sgemm sequential-k order
            float d;
            {
                #pragma clang fp contract(off)
                d = (sumx + SUME[kk]) - cc;           // fl32 grid @ ~64
            }
            WLD[q] = d;
            atomicMin(&DMIN[row], fkey(d));
        }
        __syncthreads();
        for (unsigned q = t; q < wc; q += THREADS) {
            int pr = WL[q]; int row = pr >> 10; int kk = pr & 1023;
            if (fkey(WLD[q]) == DMIN[row])
                atomicMin(&KMIN[row], (unsigned)kk);  // ties -> smallest k = first-min
        }
        __syncthreads();
        if (t < ROWS_PB) {
            int bk = (int)KMIN[t];
            SIDX[t] = bk;
            out_idx[blk_row0 + t] = (float)bk;
        }
    } else {
        // cold exact fallback (worklist overflow; never on sane data).
        if (t < ROWS_PB) {
            const float* xr = x + (blk_row0 + (size_t)t) * EMB_DIM;
            float sumx = np_sq64(xr);
            volatile const float* xv = xr;
            float bm = 3.4e38f; int bb = 0;
            for (int kk = 0; kk < NUM_EMB; ++kk) {
                const float* er = emb + (kk << 6);
                float cc = 0.f;
                for (int i = 0; i < EMB_DIM; ++i)
                    cc = fmaf(2.0f * xv[i], er[i], cc);
                {
                    #pragma clang fp contract(off)
                    float d = (sumx + SUME[kk]) - cc;
                    if (d < bm) { bm = d; bb = kk; }
                }
            }
            SIDX[t] = bb;
            out_idx[blk_row0 + t] = (float)bb;
        }
    }
    __syncthreads();

    // ---- coalesced gather: quantized[row] = emb[idx[row]]
    const float4* emb4 = reinterpret_cast<const float4*>(emb);
    float4* q4 = reinterpret_cast<float4*>(out_q + blk_row0 * EMB_DIM);
    #pragma unroll
    for (int i = 0; i < 8; ++i) {
        int e4 = t + i * THREADS;     // 8192 float4 per block
        int rr = e4 >> 4, cc2 = e4 & 15;
        q4[e4] = emb4[SIDX[rr]*16 + cc2];
    }
}

extern "C" void kernel_launch(void* const* d_in, const int* in_sizes, int n_in,
                              void* d_out, int out_size, void* d_ws, size_t ws_size,
                              hipStream_t stream) {
    const float* x   = (const float*)d_in[0];
    const float* emb = (const float*)d_in[1];
    float* out_q   = (float*)d_out;
    float* out_idx = out_q + Q_ELEMS;
    float*          sume = (float*)d_ws;                          // 4 KB
    unsigned short* ehg  = (unsigned short*)((char*)d_ws + 4096); // 128 KB bf16 emb

    vq_prep<<<dim3(NUM_EMB / 256), dim3(256), 0, stream>>>(emb, sume, ehg);
    vq_main<<<dim3(N_ROWS / ROWS_PB), dim3(THREADS), 0, stream>>>(x, emb, sume, ehg,
                                                                  out_q, out_idx);
}